// Round 2
// baseline (1335.661 us; speedup 1.0000x reference)
//
#include <hip/hip_runtime.h>
#include <math.h>

#define N_TOK 32768
#define F_DIM 1024
#define H_DIM 64

typedef __attribute__((ext_vector_type(8))) short short8;
typedef __attribute__((ext_vector_type(4))) short short4v;
typedef __attribute__((ext_vector_type(4))) float floatx4;

// round-to-nearest-even f32 -> bf16 bits
__device__ __forceinline__ short f2bf(float f) {
  unsigned u = __builtin_bit_cast(unsigned, f);
  unsigned r = (u + 0x7fffu + ((u >> 16) & 1u)) >> 16;
  return (short)r;
}

__device__ __forceinline__ float softplusf(float v) {
  float a = fabsf(v);
  float r = log1pf(expf(-a));
  return v > 0.f ? v + r : r;
}

// Build bf16 transposed weights in workspace:
//   w1t[m][h][f] = bf16(W1[m][f][h])   (rows are fc1 output cols)
//   w2t[m][f][h] = bf16(W2[m][h][f])   (rows are fc2 output cols)
__global__ void prep_weights(const float* __restrict__ W1, const float* __restrict__ W2,
                             short* __restrict__ w1t, short* __restrict__ w2t) {
  int idx = blockIdx.x * blockDim.x + threadIdx.x;
  if (idx >= 6 * 64 * 1024) return;
  {
    int f = idx & 1023;
    int mh = idx >> 10;
    int h = mh & 63;
    int m = mh >> 6;
    w1t[idx] = f2bf(W1[(m * 1024 + f) * 64 + h]);
  }
  {
    int h = idx & 63;
    int mf = idx >> 6;
    int f = mf & 1023;
    int m = mf >> 10;
    w2t[idx] = f2bf(W2[(m * 64 + h) * 1024 + f]);
  }
}

// Fully fused: per 16-token block, 4 waves (column-split).
//   stage: x tile -> LDS bf16 (one conversion per element)
//   A: h[320] = relu(x @ W1[0..4] + B1)      (wave = 80 hcols)
//   B: y_b = x + h_b @ W2_b + B2_b, act, store; q also packed bf16 -> LDS
//   C: h5 = relu(q @ W1[5] + B1[5]); out5 = x + q + h5 @ W2[5] + B2[5]
// MFMA operand order swapped (A=weights, B=activations): each lane's C/D regs are
// 4 CONSECUTIVE output cols of one token row -> float4 epilogue loads/stores.
#define XQ_STRIDE 1048  // shorts; 2096B = 131*16 -> 16B aligned rows, granule-spread banks
__global__ __launch_bounds__(256, 3) void k_fused(
    const float* __restrict__ x, const short* __restrict__ w1t,
    const float* __restrict__ b1, const short* __restrict__ w2t,
    const float* __restrict__ b2, const short* __restrict__ w1t5,
    const float* __restrict__ b1_5, const short* __restrict__ w2t5,
    const float* __restrict__ b2_5, float* __restrict__ out) {
  __shared__ short xq[16 * XQ_STRIDE];  // x (phases A) then q (phase C), bf16
  __shared__ short hlds[16 * 328];      // h[tok][320] branches 0..4; reused for h5 (stride 72)

  const int tid = threadIdx.x;
  const int lane = tid & 63;
  const int wid = tid >> 6;
  const int m16 = lane & 15;
  const int quad = lane >> 4;
  const int row0 = blockIdx.x * 16;

  // ---- stage: x -> LDS bf16. Per pass: wave wid does row pass*4+wid, lane covers
  // 2x contiguous 32B chunks (coalesced reads, conflict-free 16B LDS writes). ----
  for (int pass = 0; pass < 4; pass++) {
    const int r = pass * 4 + wid;
    const float* xr = x + (size_t)(row0 + r) * F_DIM;
#pragma unroll
    for (int j = 0; j < 2; j++) {
      const int c = j * 512 + lane * 8;
      float4 va = *(const float4*)(xr + c);
      float4 vb = *(const float4*)(xr + c + 4);
      short8 p = {f2bf(va.x), f2bf(va.y), f2bf(va.z), f2bf(va.w),
                  f2bf(vb.x), f2bf(vb.y), f2bf(vb.z), f2bf(vb.w)};
      *(short8*)(&xq[r * XQ_STRIDE + c]) = p;
    }
  }
  __syncthreads();

  // ---- Phase A: wave wid computes hcols [wid*80, wid*80+80) over 16 tokens ----
  floatx4 acc[5];
#pragma unroll
  for (int i = 0; i < 5; i++) acc[i] = (floatx4){0.f, 0.f, 0.f, 0.f};

  {
    const short* xrow = &xq[m16 * XQ_STRIDE];
    const short* w1c = w1t + (size_t)wid * 80 * 1024;
    for (int kk = 0; kk < 32; kk++) {
      const int k0 = kk * 32 + quad * 8;
      short8 a = *(const short8*)(xrow + k0);
#pragma unroll
      for (int ct = 0; ct < 5; ct++) {
        short8 w = *(const short8*)(w1c + (ct * 16 + m16) * 1024 + k0);
        // D[hcol][tok]: lane m16 = tok, regs = 4 consecutive hcols at quad*4
        acc[ct] = __builtin_amdgcn_mfma_f32_16x16x32_bf16(w, a, acc[ct], 0, 0, 0);
      }
    }
  }

#pragma unroll
  for (int ct = 0; ct < 5; ct++) {
    const int c0 = wid * 80 + ct * 16 + quad * 4;  // c = branch*64 + h
    const float4 bias = *(const float4*)(b1 + c0);
    short4v p = {f2bf(fmaxf(acc[ct][0] + bias.x, 0.f)),
                 f2bf(fmaxf(acc[ct][1] + bias.y, 0.f)),
                 f2bf(fmaxf(acc[ct][2] + bias.z, 0.f)),
                 f2bf(fmaxf(acc[ct][3] + bias.w, 0.f))};
    *(short4v*)(&hlds[m16 * 328 + c0]) = p;
  }
  __syncthreads();

  // ---- Phase B: wave wid covers out cols [wid*256, wid*256+256); x loaded ONCE per ct ----
  short8 ha[5], hb[5];
#pragma unroll
  for (int b = 0; b < 5; b++) {
    const short* hr = &hlds[m16 * 328 + b * 64];
    ha[b] = *(const short8*)(hr + quad * 8);
    hb[b] = *(const short8*)(hr + 32 + quad * 8);
  }

  const size_t gr = (size_t)row0 + m16;
  const float* xr = x + gr * F_DIM;

  for (int ct = 0; ct < 16; ct++) {
    const int col = wid * 256 + ct * 16 + quad * 4;  // 4 consecutive out cols
    const int wrow = wid * 256 + ct * 16 + m16;      // w2t row for this lane
    floatx4 xv = *(const floatx4*)(xr + col);
#pragma unroll
    for (int b = 0; b < 5; b++) {
      const short* wb = w2t + (size_t)b * (F_DIM * H_DIM) + (size_t)wrow * 64;
      short8 w0 = *(const short8*)(wb + quad * 8);
      short8 w1v = *(const short8*)(wb + 32 + quad * 8);
      floatx4 c = {0.f, 0.f, 0.f, 0.f};
      c = __builtin_amdgcn_mfma_f32_16x16x32_bf16(w0, ha[b], c, 0, 0, 0);
      c = __builtin_amdgcn_mfma_f32_16x16x32_bf16(w1v, hb[b], c, 0, 0, 0);
      floatx4 b2v = *(const floatx4*)(b2 + b * F_DIM + col);
      float y0 = c[0] + xv[0] + b2v[0];
      float y1 = c[1] + xv[1] + b2v[1];
      float y2 = c[2] + xv[2] + b2v[2];
      float y3 = c[3] + xv[3] + b2v[3];
      if (b == 3) {
        y0 = softplusf(y0); y1 = softplusf(y1);
        y2 = softplusf(y2); y3 = softplusf(y3);
      } else if (b == 4) {
        y0 = 1.f / (1.f + expf(-y0)); y1 = 1.f / (1.f + expf(-y1));
        y2 = 1.f / (1.f + expf(-y2)); y3 = 1.f / (1.f + expf(-y3));
      }
      floatx4 y = {y0, y1, y2, y3};
      float* op = out + (size_t)b * N_TOK * F_DIM + gr * F_DIM + col;
      if (b == 2) {
        *(floatx4*)op = y;  // q re-read (f32) below: keep cacheable
        short4v qp = {f2bf(y0), f2bf(y1), f2bf(y2), f2bf(y3)};
        *(short4v*)(&xq[m16 * XQ_STRIDE + col]) = qp;  // q bf16 for phase C fc1
      } else {
        __builtin_nontemporal_store(y, (floatx4*)op);  // write-only streams
      }
    }
  }
  __syncthreads();

  // ---- Phase C: branch 5. fc1: wave wid computes hcols [wid*16, wid*16+16) ----
  {
    floatx4 acc5 = {0.f, 0.f, 0.f, 0.f};
    const short* qrow = &xq[m16 * XQ_STRIDE];
    const short* w5 = w1t5 + (size_t)(wid * 16 + m16) * 1024;
    for (int kk = 0; kk < 32; kk++) {
      const int k0 = kk * 32 + quad * 8;
      short8 qf = *(const short8*)(qrow + k0);
      short8 w = *(const short8*)(w5 + k0);
      acc5 = __builtin_amdgcn_mfma_f32_16x16x32_bf16(w, qf, acc5, 0, 0, 0);
    }
    const int c0 = wid * 16 + quad * 4;
    const float4 bias = *(const float4*)(b1_5 + c0);
    short4v p = {f2bf(fmaxf(acc5[0] + bias.x, 0.f)),
                 f2bf(fmaxf(acc5[1] + bias.y, 0.f)),
                 f2bf(fmaxf(acc5[2] + bias.z, 0.f)),
                 f2bf(fmaxf(acc5[3] + bias.w, 0.f))};
    *(short4v*)(&hlds[m16 * 72 + c0]) = p;  // hlds reused (phase-B reads done pre-sync)
  }
  __syncthreads();

  // fc2: out5 = x + q + h5 @ W2[5] + B2[5]; x,q re-read f32 from global (L2-hot)
  {
    short8 ha5 = *(const short8*)(&hlds[m16 * 72 + quad * 8]);
    short8 hb5 = *(const short8*)(&hlds[m16 * 72 + 32 + quad * 8]);
    const float* qr = out + (size_t)2 * N_TOK * F_DIM + gr * F_DIM;
    float* o5 = out + (size_t)5 * N_TOK * F_DIM + gr * F_DIM;
    for (int ct = 0; ct < 16; ct++) {
      const int col = wid * 256 + ct * 16 + quad * 4;
      const int wrow = wid * 256 + ct * 16 + m16;
      const short* wb = w2t5 + (size_t)wrow * 64;
      short8 w0 = *(const short8*)(wb + quad * 8);
      short8 w1v = *(const short8*)(wb + 32 + quad * 8);
      floatx4 c = {0.f, 0.f, 0.f, 0.f};
      c = __builtin_amdgcn_mfma_f32_16x16x32_bf16(w0, ha5, c, 0, 0, 0);
      c = __builtin_amdgcn_mfma_f32_16x16x32_bf16(w1v, hb5, c, 0, 0, 0);
      floatx4 xv = *(const floatx4*)(xr + col);
      floatx4 qv = *(const floatx4*)(qr + col);
      floatx4 b2v = *(const floatx4*)(b2_5 + col);
      floatx4 y = {c[0] + xv[0] + qv[0] + b2v[0],
                   c[1] + xv[1] + qv[1] + b2v[1],
                   c[2] + xv[2] + qv[2] + b2v[2],
                   c[3] + xv[3] + qv[3] + b2v[3]};
      __builtin_nontemporal_store(y, (floatx4*)(o5 + col));
    }
  }
}

extern "C" void kernel_launch(void* const* d_in, const int* in_sizes, int n_in,
                              void* d_out, int out_size, void* d_ws, size_t ws_size,
                              hipStream_t stream) {
  const float* x = (const float*)d_in[0];
  const float* W1 = (const float*)d_in[1];
  const float* B1 = (const float*)d_in[2];
  const float* W2 = (const float*)d_in[3];
  const float* B2 = (const float*)d_in[4];
  float* out = (float*)d_out;

  short* w1t = (short*)d_ws;                // [6][64][1024] bf16
  short* w2t = w1t + 6 * 64 * 1024;         // [6][1024][64] bf16  (1.5 MB total ws)

  prep_weights<<<(6 * 64 * 1024 + 255) / 256, 256, 0, stream>>>(W1, W2, w1t, w2t);

  k_fused<<<N_TOK / 16, 256, 0, stream>>>(x, w1t, B1, w2t, B2,
                                          w1t + 5 * 64 * 1024, B1 + 5 * 64,
                                          w2t + 5 * 1024 * 64, B2 + 5 * 1024, out);
}